// Round 1
// baseline (669.709 us; speedup 1.0000x reference)
//
#include <hip/hip_runtime.h>
#include <cstdint>
#include <cstddef>

#define NN 250000   // nodes
#define FF 256      // channels
#define GG 4096     // graphs
#define TT 6        // processing steps

typedef _Float16 half8_t __attribute__((ext_vector_type(8)));
typedef float f32x4 __attribute__((ext_vector_type(4)));

// ---------------- one-time prep ----------------
// W_comb[j][k] = Wih[j][k] + (k<256 ? Whh[j][k] : 0), cast to f16.  bias = bih+bhh.
__global__ __launch_bounds__(256) void prep_w_kernel(
    const float* __restrict__ Wih, const float* __restrict__ Whh,
    const float* __restrict__ bih, const float* __restrict__ bhh,
    _Float16* __restrict__ w16, float* __restrict__ bias) {
  int idx = blockIdx.x * 256 + threadIdx.x;
  if (idx < 4 * FF) bias[idx] = bih[idx] + bhh[idx];
  if (idx >= 4 * FF * 2 * FF) return;
  int j = idx >> 9;          // gate row 0..1023
  int k = idx & 511;         // k 0..511
  float v = Wih[(size_t)j * (2 * FF) + k];
  if (k < FF) v += Whh[(size_t)j * FF + k];
  w16[idx] = (_Float16)v;
}

// starts[g] = lower_bound(batch, g); starts[GG] = NN   (batch is sorted)
__global__ __launch_bounds__(256) void find_starts_kernel(
    const int* __restrict__ batch, int* __restrict__ starts) {
  int g = blockIdx.x * 256 + threadIdx.x;
  if (g > GG) return;
  if (g == GG) { starts[GG] = NN; return; }
  int lo = 0, hi = NN;
  while (lo < hi) {
    int mid = (lo + hi) >> 1;
    if (batch[mid] < g) lo = mid + 1; else hi = mid;
  }
  starts[g] = lo;
}

// ---------------- LSTM gates GEMM ----------------
// gates[4096,1024] = q16[4096,512] @ w16^T   (f16 in, f32 acc)
// Block: 256 thr = 4 waves (2x2).  Per wave: 64(M) x 32(N), 4x2 frags of 16x16.
// Frag layout (gfx950 16x16x32): A lane l holds A[l&15][ (l>>4)*8 + i ],
// B lane l holds B[(l>>4)*8 + i][l&15], D lane l reg r = D[(l>>4)*4 + r][l&15].
__global__ __launch_bounds__(256) void gemm_gates_kernel(
    const _Float16* __restrict__ q16, const _Float16* __restrict__ w16,
    float* __restrict__ gates) {
  int lane = threadIdx.x & 63;
  int w    = threadIdx.x >> 6;
  int wm   = w >> 1, wn = w & 1;
  int m0 = blockIdx.x * 128 + wm * 64;   // graph rows
  int n0 = blockIdx.y * 64  + wn * 32;   // gate cols
  int lr = lane & 15;
  int kq = lane >> 4;

  f32x4 acc[4][2];
#pragma unroll
  for (int m = 0; m < 4; ++m)
#pragma unroll
    for (int n = 0; n < 2; ++n) acc[m][n] = (f32x4){0.f, 0.f, 0.f, 0.f};

#pragma unroll 2
  for (int k0 = 0; k0 < 512; k0 += 32) {
    int kk = k0 + kq * 8;
    half8_t a[4], b[2];
#pragma unroll
    for (int m = 0; m < 4; ++m)
      a[m] = *(const half8_t*)(q16 + (size_t)(m0 + m * 16 + lr) * 512 + kk);
#pragma unroll
    for (int n = 0; n < 2; ++n)
      b[n] = *(const half8_t*)(w16 + (size_t)(n0 + n * 16 + lr) * 512 + kk);
#pragma unroll
    for (int m = 0; m < 4; ++m)
#pragma unroll
      for (int n = 0; n < 2; ++n)
        acc[m][n] = __builtin_amdgcn_mfma_f32_16x16x32_f16(a[m], b[n], acc[m][n], 0, 0, 0);
  }

  int rbase = kq * 4;
#pragma unroll
  for (int m = 0; m < 4; ++m)
#pragma unroll
    for (int n = 0; n < 2; ++n)
#pragma unroll
      for (int r = 0; r < 4; ++r)
        gates[(size_t)(m0 + m * 16 + rbase + r) * 1024 + (n0 + n * 16 + lr)] = acc[m][n][r];
}

// ---------------- LSTM pointwise ----------------
__global__ __launch_bounds__(256) void lstm_pointwise_kernel(
    const float* __restrict__ gates, const float* __restrict__ bias,
    float* __restrict__ c, float* __restrict__ qstar, _Float16* __restrict__ q16) {
  int idx = blockIdx.x * 256 + threadIdx.x;  // g*256 + f
  int g = idx >> 8;
  int f = idx & 255;
  const float* grow = gates + (size_t)g * 1024;
  float ig = grow[f]       + bias[f];
  float fg = grow[f + 256] + bias[f + 256];
  float gg = grow[f + 512] + bias[f + 512];
  float og = grow[f + 768] + bias[f + 768];
  float si = 1.f / (1.f + __expf(-ig));
  float sf = 1.f / (1.f + __expf(-fg));
  float so = 1.f / (1.f + __expf(-og));
  float cv = sf * c[idx] + si * tanhf(gg);
  float hv = so * tanhf(cv);
  c[idx] = cv;
  qstar[(size_t)g * 512 + f] = hv;            // q half of q_star
  q16[(size_t)g * 512 + f] = (_Float16)hv;    // f16 mirror for next GEMM
}

// ---------------- attention + segment softmax + readout ----------------
// One block (4 waves) per graph; nodes are contiguous [starts[g], starts[g+1]).
__global__ __launch_bounds__(256) void attn_kernel(
    const float* __restrict__ x, const int* __restrict__ starts,
    float* __restrict__ qstar, _Float16* __restrict__ q16,
    float* __restrict__ e_buf) {
  int g   = blockIdx.x;
  int s0  = starts[g];
  int cnt = starts[g + 1] - s0;
  int tid = threadIdx.x;
  int lane = tid & 63;
  int w    = tid >> 6;

  __shared__ float wred[4];
  __shared__ float rpart[4][FF];

  // q fragment: lane holds channels 4*lane .. 4*lane+3 (q == q_star[:, :256])
  f32x4 qv = *(const f32x4*)(qstar + (size_t)g * 512 + lane * 4);

  // pass 1: e_n = x[n]·q, track max.  One node per wave per iteration.
  float mloc = -INFINITY;
  for (int i = w; i < cnt; i += 4) {
    f32x4 xv = *(const f32x4*)(x + (size_t)(s0 + i) * FF + lane * 4);
    float d = xv[0] * qv[0] + xv[1] * qv[1] + xv[2] * qv[2] + xv[3] * qv[3];
#pragma unroll
    for (int off = 32; off > 0; off >>= 1) d += __shfl_xor(d, off);
    if (lane == 0) e_buf[s0 + i] = d;
    mloc = fmaxf(mloc, d);
  }
  if (lane == 0) wred[w] = mloc;
  __syncthreads();
  float m = fmaxf(fmaxf(wred[0], wred[1]), fmaxf(wred[2], wred[3]));
  __syncthreads();   // protect wred reuse + make pass-1 e_buf visible

  // pass 2: ex = exp(e-m) (overwrite e_buf), denom = sum ex
  float part = 0.f;
  for (int i = tid; i < cnt; i += 256) {
    float v = __expf(e_buf[s0 + i] - m);
    e_buf[s0 + i] = v;
    part += v;
  }
#pragma unroll
  for (int off = 32; off > 0; off >>= 1) part += __shfl_xor(part, off);
  if (lane == 0) wred[w] = part;
  __syncthreads();
  float denom = wred[0] + wred[1] + wred[2] + wred[3];
  float inv = 1.0f / (denom + 1e-16f);

  // pass 3: r = (sum ex_n * x[n]) * inv.  One node per wave, float4 channels/lane.
  f32x4 racc = {0.f, 0.f, 0.f, 0.f};
  for (int i = w; i < cnt; i += 4) {
    float a = e_buf[s0 + i];
    f32x4 xv = *(const f32x4*)(x + (size_t)(s0 + i) * FF + lane * 4);
    racc[0] += a * xv[0]; racc[1] += a * xv[1];
    racc[2] += a * xv[2]; racc[3] += a * xv[3];
  }
#pragma unroll
  for (int jj = 0; jj < 4; ++jj) rpart[w][lane * 4 + jj] = racc[jj];
  __syncthreads();
  float r = (rpart[0][tid] + rpart[1][tid] + rpart[2][tid] + rpart[3][tid]) * inv;
  qstar[(size_t)g * 512 + FF + tid] = r;          // r half of q_star
  q16[(size_t)g * 512 + FF + tid] = (_Float16)r;  // f16 mirror
}

// ---------------- launcher ----------------
extern "C" void kernel_launch(void* const* d_in, const int* in_sizes, int n_in,
                              void* d_out, int out_size, void* d_ws, size_t ws_size,
                              hipStream_t stream) {
  const float* x   = (const float*)d_in[0];
  const int* batch = (const int*)d_in[1];
  // d_in[2] = size (4096), unused — hard-coded
  const float* Wih = (const float*)d_in[3];
  const float* Whh = (const float*)d_in[4];
  const float* bih = (const float*)d_in[5];
  const float* bhh = (const float*)d_in[6];
  float* qstar = (float*)d_out;  // [GG, 512]; final value IS the output

  uint8_t* p = (uint8_t*)d_ws;
  float* c_st   = (float*)p;    p += (size_t)GG * FF * 4;             // 4 MB
  float* gates  = (float*)p;    p += (size_t)GG * 4 * FF * 4;         // 16.8 MB
  _Float16* q16 = (_Float16*)p; p += (size_t)GG * 2 * FF * 2;         // 4 MB
  _Float16* w16 = (_Float16*)p; p += (size_t)(4 * FF) * (2 * FF) * 2; // 1 MB
  float* bias   = (float*)p;    p += (size_t)(4 * FF) * 4;            // 4 KB
  float* e_buf  = (float*)p;    p += ((size_t)NN * 4 + 255) / 256 * 256; // 1 MB
  int* starts   = (int*)p;      p += (size_t)(GG + 1) * 4;

  hipMemsetAsync(d_out, 0, (size_t)GG * 2 * FF * 4, stream);
  hipMemsetAsync(c_st, 0, (size_t)GG * FF * 4, stream);
  hipMemsetAsync(q16, 0, (size_t)GG * 2 * FF * 2, stream);

  prep_w_kernel<<<(4 * FF * 2 * FF + 255) / 256, 256, 0, stream>>>(
      Wih, Whh, bih, bhh, w16, bias);
  find_starts_kernel<<<(GG + 1 + 255) / 256, 256, 0, stream>>>(batch, starts);

  for (int t = 0; t < TT; ++t) {
    gemm_gates_kernel<<<dim3(32, 16), 256, 0, stream>>>(q16, w16, gates);
    lstm_pointwise_kernel<<<GG, 256, 0, stream>>>(gates, bias, c_st, qstar, q16);
    attn_kernel<<<GG, 256, 0, stream>>>(x, starts, qstar, q16, e_buf);
  }
}

// Round 2
// 386.421 us; speedup vs baseline: 1.7331x; 1.7331x over previous
//
#include <hip/hip_runtime.h>
#include <cstdint>
#include <cstddef>

#define NN 250000   // nodes
#define FF 256      // channels
#define GG 4096     // graphs
#define TT 6        // processing steps

typedef _Float16 half8_t __attribute__((ext_vector_type(8)));
typedef _Float16 half4_t __attribute__((ext_vector_type(4)));
typedef float f32x4 __attribute__((ext_vector_type(4)));

// ---------------- one-time prep ----------------
// W_comb[j][k] = Wih[j][k] + (k<256 ? Whh[j][k] : 0), cast to f16.  bias = bih+bhh.
__global__ __launch_bounds__(256) void prep_w_kernel(
    const float* __restrict__ Wih, const float* __restrict__ Whh,
    const float* __restrict__ bih, const float* __restrict__ bhh,
    _Float16* __restrict__ w16, float* __restrict__ bias) {
  int idx = blockIdx.x * 256 + threadIdx.x;
  if (idx < 4 * FF) bias[idx] = bih[idx] + bhh[idx];
  if (idx >= 4 * FF * 2 * FF) return;
  int j = idx >> 9;          // gate row 0..1023
  int k = idx & 511;         // k 0..511
  float v = Wih[(size_t)j * (2 * FF) + k];
  if (k < FF) v += Whh[(size_t)j * FF + k];
  w16[idx] = (_Float16)v;
}

// starts[g] = lower_bound(batch, g); starts[GG] = NN   (batch is sorted)
__global__ __launch_bounds__(256) void find_starts_kernel(
    const int* __restrict__ batch, int* __restrict__ starts) {
  int g = blockIdx.x * 256 + threadIdx.x;
  if (g > GG) return;
  if (g == GG) { starts[GG] = NN; return; }
  int lo = 0, hi = NN;
  while (lo < hi) {
    int mid = (lo + hi) >> 1;
    if (batch[mid] < g) lo = mid + 1; else hi = mid;
  }
  starts[g] = lo;
}

// ---------------- LSTM gates GEMM (validated in R1, unchanged) ----------------
// gates[4096,1024] = q16[4096,512] @ w16^T   (f16 in, f32 acc)
__global__ __launch_bounds__(256) void gemm_gates_kernel(
    const _Float16* __restrict__ q16, const _Float16* __restrict__ w16,
    float* __restrict__ gates) {
  int lane = threadIdx.x & 63;
  int w    = threadIdx.x >> 6;
  int wm   = w >> 1, wn = w & 1;
  int m0 = blockIdx.x * 128 + wm * 64;   // graph rows
  int n0 = blockIdx.y * 64  + wn * 32;   // gate cols
  int lr = lane & 15;
  int kq = lane >> 4;

  f32x4 acc[4][2];
#pragma unroll
  for (int m = 0; m < 4; ++m)
#pragma unroll
    for (int n = 0; n < 2; ++n) acc[m][n] = (f32x4){0.f, 0.f, 0.f, 0.f};

#pragma unroll 2
  for (int k0 = 0; k0 < 512; k0 += 32) {
    int kk = k0 + kq * 8;
    half8_t a[4], b[2];
#pragma unroll
    for (int m = 0; m < 4; ++m)
      a[m] = *(const half8_t*)(q16 + (size_t)(m0 + m * 16 + lr) * 512 + kk);
#pragma unroll
    for (int n = 0; n < 2; ++n)
      b[n] = *(const half8_t*)(w16 + (size_t)(n0 + n * 16 + lr) * 512 + kk);
#pragma unroll
    for (int m = 0; m < 4; ++m)
#pragma unroll
      for (int n = 0; n < 2; ++n)
        acc[m][n] = __builtin_amdgcn_mfma_f32_16x16x32_f16(a[m], b[n], acc[m][n], 0, 0, 0);
  }

  int rbase = kq * 4;
#pragma unroll
  for (int m = 0; m < 4; ++m)
#pragma unroll
    for (int n = 0; n < 2; ++n)
#pragma unroll
      for (int r = 0; r < 4; ++r)
        gates[(size_t)(m0 + m * 16 + rbase + r) * 1024 + (n0 + n * 16 + lr)] = acc[m][n][r];
}

// ---------------- fused LSTM-pointwise + single-pass attention ----------------
// One block (4 waves) per graph. Online softmax: one sweep over the graph's
// contiguous nodes computes max / exp-sum / weighted accumulator together.
// XMODE: 0 = read x32 (fallback), 1 = read x32 + write x16 (step 0),
//        2 = read x16 (steps 1..5).
template <bool HAS_GATES, int XMODE>
__global__ __launch_bounds__(256) void step_kernel(
    const float* __restrict__ x32, const _Float16* __restrict__ x16r,
    _Float16* __restrict__ x16w, const int* __restrict__ starts,
    const float* __restrict__ gates, const float* __restrict__ bias,
    float* __restrict__ c, float* __restrict__ qstar,
    _Float16* __restrict__ q16) {
  int g = blockIdx.x;
  int tid = threadIdx.x;
  int lane = tid & 63;
  int w = tid >> 6;

  // ---- LSTM pointwise: thread tid owns channel tid of graph g ----
  float ig = bias[tid];
  float fg = bias[tid + 256];
  float gg = bias[tid + 512];
  float og = bias[tid + 768];
  float cv;
  if (HAS_GATES) {
    const float* grow = gates + (size_t)g * 1024;
    ig += grow[tid]; fg += grow[tid + 256];
    gg += grow[tid + 512]; og += grow[tid + 768];
    float si = 1.f / (1.f + __expf(-ig));
    float sf = 1.f / (1.f + __expf(-fg));
    cv = sf * c[(size_t)g * FF + tid] + si * tanhf(gg);
  } else {
    // t == 0: gates GEMM output is identically 0 (q_star = h = 0), c = 0
    float si = 1.f / (1.f + __expf(-ig));
    cv = si * tanhf(gg);
  }
  float so = 1.f / (1.f + __expf(-og));
  float hv = so * tanhf(cv);
  c[(size_t)g * FF + tid] = cv;
  qstar[(size_t)g * 512 + tid] = hv;          // q half of q_star
  q16[(size_t)g * 512 + tid] = (_Float16)hv;  // f16 mirror for next GEMM

  __shared__ __align__(16) float h_sh[FF];
  __shared__ __align__(16) float rw[4][FF];
  __shared__ float mw[4], sw[4];
  h_sh[tid] = hv;
  __syncthreads();

  // q fragment: lane holds channels 4*lane .. 4*lane+3
  f32x4 qv = *(const f32x4*)&h_sh[4 * lane];

  int s0 = starts[g];
  int cnt = starts[g + 1] - s0;

  // ---- online-softmax sweep: one node per wave per iteration ----
  float m = -INFINITY, ssum = 0.f;
  f32x4 racc = {0.f, 0.f, 0.f, 0.f};
  for (int i = w; i < cnt; i += 4) {
    f32x4 xv;
    if (XMODE == 2) {
      half4_t hx = *(const half4_t*)(x16r + (size_t)(s0 + i) * FF + 4 * lane);
      xv[0] = (float)hx[0]; xv[1] = (float)hx[1];
      xv[2] = (float)hx[2]; xv[3] = (float)hx[3];
    } else {
      xv = *(const f32x4*)(x32 + (size_t)(s0 + i) * FF + 4 * lane);
      if (XMODE == 1) {
        half4_t hx;
        hx[0] = (_Float16)xv[0]; hx[1] = (_Float16)xv[1];
        hx[2] = (_Float16)xv[2]; hx[3] = (_Float16)xv[3];
        *(half4_t*)(x16w + (size_t)(s0 + i) * FF + 4 * lane) = hx;
      }
    }
    float d = xv[0] * qv[0] + xv[1] * qv[1] + xv[2] * qv[2] + xv[3] * qv[3];
#pragma unroll
    for (int off = 32; off; off >>= 1) d += __shfl_xor(d, off);
    if (d > m) {  // wave-uniform (d identical across lanes after reduction)
      float sc = __expf(m - d);  // first iter: exp(-inf)=0, zeroes nothing
      ssum *= sc;
      racc[0] *= sc; racc[1] *= sc; racc[2] *= sc; racc[3] *= sc;
      m = d;
    }
    float p = __expf(d - m);
    ssum += p;
    racc[0] += p * xv[0]; racc[1] += p * xv[1];
    racc[2] += p * xv[2]; racc[3] += p * xv[3];
  }

  // ---- merge 4 waves ----
  if (lane == 0) { mw[w] = m; sw[w] = ssum; }
  *(f32x4*)&rw[w][4 * lane] = racc;
  __syncthreads();
  float M = fmaxf(fmaxf(mw[0], mw[1]), fmaxf(mw[2], mw[3]));
  float e0 = __expf(mw[0] - M), e1 = __expf(mw[1] - M);
  float e2 = __expf(mw[2] - M), e3 = __expf(mw[3] - M);
  float denom = sw[0] * e0 + sw[1] * e1 + sw[2] * e2 + sw[3] * e3;
  float rsum = rw[0][tid] * e0 + rw[1][tid] * e1 + rw[2][tid] * e2 + rw[3][tid] * e3;
  float r = rsum / (denom + 1e-16f);
  if (cnt == 0) r = 0.f;  // empty graph: reference gives 0/(0+1e-16) = 0
  qstar[(size_t)g * 512 + FF + tid] = r;
  q16[(size_t)g * 512 + FF + tid] = (_Float16)r;
}

// ---------------- launcher ----------------
extern "C" void kernel_launch(void* const* d_in, const int* in_sizes, int n_in,
                              void* d_out, int out_size, void* d_ws, size_t ws_size,
                              hipStream_t stream) {
  const float* x   = (const float*)d_in[0];
  const int* batch = (const int*)d_in[1];
  // d_in[2] = size (4096), hard-coded
  const float* Wih = (const float*)d_in[3];
  const float* Whh = (const float*)d_in[4];
  const float* bih = (const float*)d_in[5];
  const float* bhh = (const float*)d_in[6];
  float* qstar = (float*)d_out;  // [GG, 512]; final value IS the output

  uint8_t* p = (uint8_t*)d_ws;
  auto alloc = [&](size_t bytes) {
    uint8_t* q = p;
    p += (bytes + 255) & ~(size_t)255;
    return q;
  };
  float* c_st    = (float*)alloc((size_t)GG * FF * 4);          // 4 MB
  float* gates   = (float*)alloc((size_t)GG * 4 * FF * 4);      // 16.8 MB
  _Float16* q16  = (_Float16*)alloc((size_t)GG * 2 * FF * 2);   // 4 MB
  _Float16* w16  = (_Float16*)alloc((size_t)4 * FF * 2 * FF * 2); // 1 MB
  float* bias    = (float*)alloc((size_t)4 * FF * 4);
  int* starts    = (int*)alloc((size_t)(GG + 1) * 4);
  _Float16* x16  = (_Float16*)alloc((size_t)NN * FF * 2);       // 128 MB
  bool use16 = ((size_t)(p - (uint8_t*)d_ws) <= ws_size);

  prep_w_kernel<<<(4 * FF * 2 * FF + 255) / 256, 256, 0, stream>>>(
      Wih, Whh, bih, bhh, w16, bias);
  find_starts_kernel<<<(GG + 1 + 255) / 256, 256, 0, stream>>>(batch, starts);

  if (use16) {
    // step 0: no gates (GEMM of zeros), read x32, write x16 mirror
    step_kernel<false, 1><<<GG, 256, 0, stream>>>(
        x, nullptr, x16, starts, gates, bias, c_st, qstar, q16);
    for (int t = 1; t < TT; ++t) {
      gemm_gates_kernel<<<dim3(32, 16), 256, 0, stream>>>(q16, w16, gates);
      step_kernel<true, 2><<<GG, 256, 0, stream>>>(
          nullptr, x16, nullptr, starts, gates, bias, c_st, qstar, q16);
    }
  } else {  // workspace too small for x16 mirror: f32 path, still single-pass
    step_kernel<false, 0><<<GG, 256, 0, stream>>>(
        x, nullptr, nullptr, starts, gates, bias, c_st, qstar, q16);
    for (int t = 1; t < TT; ++t) {
      gemm_gates_kernel<<<dim3(32, 16), 256, 0, stream>>>(q16, w16, gates);
      step_kernel<true, 0><<<GG, 256, 0, stream>>>(
          x, nullptr, nullptr, starts, gates, bias, c_st, qstar, q16);
    }
  }
}

// Round 3
// 366.008 us; speedup vs baseline: 1.8298x; 1.0558x over previous
//
#include <hip/hip_runtime.h>
#include <cstdint>
#include <cstddef>

#define NN 250000   // nodes
#define FF 256      // channels
#define GG 4096     // graphs
#define TT 6        // processing steps

typedef _Float16 half8_t __attribute__((ext_vector_type(8)));
typedef _Float16 half4_t __attribute__((ext_vector_type(4)));
typedef float f32x4 __attribute__((ext_vector_type(4)));

// ---------------- one-time prep ----------------
// W_comb[j][k] = Wih[j][k] + (k<256 ? Whh[j][k] : 0), cast f16. bias = bih+bhh.
__global__ __launch_bounds__(256) void prep_w_kernel(
    const float* __restrict__ Wih, const float* __restrict__ Whh,
    const float* __restrict__ bih, const float* __restrict__ bhh,
    _Float16* __restrict__ w16, float* __restrict__ bias) {
  int idx = blockIdx.x * 256 + threadIdx.x;
  if (idx < 4 * FF) bias[idx] = bih[idx] + bhh[idx];
  if (idx >= 4 * FF * 2 * FF) return;
  int j = idx >> 9;
  int k = idx & 511;
  float v = Wih[(size_t)j * (2 * FF) + k];
  if (k < FF) v += Whh[(size_t)j * FF + k];
  w16[idx] = (_Float16)v;
}

// starts[g] = lower_bound(batch, g); starts[GG] = NN  (batch sorted)
__global__ __launch_bounds__(256) void find_starts_kernel(
    const int* __restrict__ batch, int* __restrict__ starts) {
  int g = blockIdx.x * 256 + threadIdx.x;
  if (g > GG) return;
  if (g == GG) { starts[GG] = NN; return; }
  int lo = 0, hi = NN;
  while (lo < hi) {
    int mid = (lo + hi) >> 1;
    if (batch[mid] < g) lo = mid + 1; else hi = mid;
  }
  starts[g] = lo;
}

// ---------------- fused gates-GEMM + LSTM pointwise ----------------
// Block: 64 graphs x 32 f-channels; computes W-cols {f, f+256, f+512, f+768}
// so each thread holds all 4 gates of its (g,f) -> pointwise in-register.
// Grid (GG/64, FF/32) = (64, 8). Waves 2x2: wave = 32 g x 16 f.
__global__ __launch_bounds__(256) void gemm_lstm_kernel(
    const _Float16* __restrict__ q16in, const _Float16* __restrict__ w16,
    const float* __restrict__ bias, float* __restrict__ c,
    float* __restrict__ qstar, _Float16* __restrict__ q16out) {
  int lane = threadIdx.x & 63;
  int w    = threadIdx.x >> 6;
  int wm = w >> 1, wn = w & 1;
  int g0 = blockIdx.x * 64 + wm * 32;   // graph rows (A rows)
  int f0 = blockIdx.y * 32 + wn * 16;   // f-channel (per-gate col offset)
  int lr = lane & 15, kq = lane >> 4;

  f32x4 acc[2][4];
#pragma unroll
  for (int m = 0; m < 2; ++m)
#pragma unroll
    for (int gt = 0; gt < 4; ++gt) acc[m][gt] = (f32x4){0.f, 0.f, 0.f, 0.f};

  for (int k0 = 0; k0 < 512; k0 += 32) {
    int kk = k0 + kq * 8;
    half8_t a[2], b[4];
#pragma unroll
    for (int m = 0; m < 2; ++m)
      a[m] = *(const half8_t*)(q16in + (size_t)(g0 + m * 16 + lr) * 512 + kk);
#pragma unroll
    for (int gt = 0; gt < 4; ++gt)
      b[gt] = *(const half8_t*)(w16 + (size_t)(gt * 256 + f0 + lr) * 512 + kk);
#pragma unroll
    for (int m = 0; m < 2; ++m)
#pragma unroll
      for (int gt = 0; gt < 4; ++gt)
        acc[m][gt] = __builtin_amdgcn_mfma_f32_16x16x32_f16(a[m], b[gt], acc[m][gt], 0, 0, 0);
  }

  // epilogue: LSTM pointwise fully in-register
  int f = f0 + lr;
#pragma unroll
  for (int m = 0; m < 2; ++m)
#pragma unroll
    for (int r = 0; r < 4; ++r) {
      int g = g0 + m * 16 + kq * 4 + r;
      float ig = acc[m][0][r] + bias[f];
      float fg = acc[m][1][r] + bias[f + 256];
      float gv = acc[m][2][r] + bias[f + 512];
      float og = acc[m][3][r] + bias[f + 768];
      float si = 1.f / (1.f + __expf(-ig));
      float sf = 1.f / (1.f + __expf(-fg));
      float so = 1.f / (1.f + __expf(-og));
      size_t ci = (size_t)g * FF + f;
      float cv = sf * c[ci] + si * tanhf(gv);
      float hv = so * tanhf(cv);
      c[ci] = cv;
      qstar[(size_t)g * 512 + f] = hv;
      q16out[(size_t)g * 512 + f] = (_Float16)hv;
    }
}

// ---------------- single-pass attention (online softmax) ----------------
// One block (4 waves) per graph; 4-node groups per wave for ILP.
// T0: t==0 — h = f(bias) computed in-kernel (GEMM output is identically 0).
// XMODE: 0 = read x32, 1 = read x32 (non-temporal) + write x16, 2 = read x16.
template <bool T0, int XMODE>
__global__ __launch_bounds__(256) void attn_kernel(
    const float* __restrict__ x32, const _Float16* __restrict__ x16r,
    _Float16* __restrict__ x16w, const int* __restrict__ starts,
    const float* __restrict__ bias, float* __restrict__ c,
    float* __restrict__ qstar, _Float16* __restrict__ q16out) {
  int g = blockIdx.x;
  int tid = threadIdx.x;
  int lane = tid & 63;
  int w = tid >> 6;

  __shared__ __align__(16) float rw[4][FF];
  __shared__ float mw[4], sw[4];

  f32x4 qv;
  if (T0) {
    // t = 0: gates = bias only (q_star = h = c = 0)
    __shared__ __align__(16) float h_sh[FF];
    float ig = bias[tid], fg2 = bias[tid + 512], og = bias[tid + 768];
    float si = 1.f / (1.f + __expf(-ig));
    float so = 1.f / (1.f + __expf(-og));
    float cv = si * tanhf(fg2);
    float hv = so * tanhf(cv);
    c[(size_t)g * FF + tid] = cv;
    qstar[(size_t)g * 512 + tid] = hv;
    q16out[(size_t)g * 512 + tid] = (_Float16)hv;
    h_sh[tid] = hv;
    __syncthreads();
    qv = *(const f32x4*)&h_sh[4 * lane];
  } else {
    qv = *(const f32x4*)(qstar + (size_t)g * 512 + 4 * lane);
  }

  int s0 = starts[g];
  int cnt = starts[g + 1] - s0;

  float m = -INFINITY, ssum = 0.f;
  f32x4 racc = {0.f, 0.f, 0.f, 0.f};
  for (int i0 = w * 4; i0 < cnt; i0 += 16) {
    int nv = cnt - i0;  // >= 1; group size min(4, nv)
    f32x4 xv[4];
    float dj[4];
#pragma unroll
    for (int j = 0; j < 4; ++j) {
      dj[j] = 0.f;
      xv[j] = (f32x4){0.f, 0.f, 0.f, 0.f};
      if (j < nv) {
        if (XMODE == 2) {
          half4_t hx = *(const half4_t*)(x16r + (size_t)(s0 + i0 + j) * FF + 4 * lane);
          xv[j][0] = (float)hx[0]; xv[j][1] = (float)hx[1];
          xv[j][2] = (float)hx[2]; xv[j][3] = (float)hx[3];
        } else {
          const f32x4* src = (const f32x4*)(x32 + (size_t)(s0 + i0 + j) * FF + 4 * lane);
          xv[j] = (XMODE == 1) ? __builtin_nontemporal_load(src) : *src;
          if (XMODE == 1) {
            half4_t hx;
            hx[0] = (_Float16)xv[j][0]; hx[1] = (_Float16)xv[j][1];
            hx[2] = (_Float16)xv[j][2]; hx[3] = (_Float16)xv[j][3];
            *(half4_t*)(x16w + (size_t)(s0 + i0 + j) * FF + 4 * lane) = hx;
          }
        }
        dj[j] = xv[j][0] * qv[0] + xv[j][1] * qv[1] + xv[j][2] * qv[2] + xv[j][3] * qv[3];
      }
    }
    // 4 interleaved 64-lane reductions (independent chains hide shfl latency)
#pragma unroll
    for (int off = 32; off; off >>= 1)
#pragma unroll
      for (int j = 0; j < 4; ++j) dj[j] += __shfl_xor(dj[j], off);
    float gm = dj[0];
#pragma unroll
    for (int j = 1; j < 4; ++j) if (j < nv) gm = fmaxf(gm, dj[j]);
    if (gm > m) {  // wave-uniform; one rescale per 4-node group
      float sc = __expf(m - gm);
      ssum *= sc; racc *= sc;
      m = gm;
    }
#pragma unroll
    for (int j = 0; j < 4; ++j) if (j < nv) {
      float p = __expf(dj[j] - m);
      ssum += p;
      racc += p * xv[j];
    }
  }

  // merge the 4 waves
  if (lane == 0) { mw[w] = m; sw[w] = ssum; }
  *(f32x4*)&rw[w][4 * lane] = racc;
  __syncthreads();
  float M = fmaxf(fmaxf(mw[0], mw[1]), fmaxf(mw[2], mw[3]));
  float e0 = __expf(mw[0] - M), e1 = __expf(mw[1] - M);
  float e2 = __expf(mw[2] - M), e3 = __expf(mw[3] - M);
  float denom = sw[0] * e0 + sw[1] * e1 + sw[2] * e2 + sw[3] * e3;
  float rsum = rw[0][tid] * e0 + rw[1][tid] * e1 + rw[2][tid] * e2 + rw[3][tid] * e3;
  float r = rsum / (denom + 1e-16f);
  if (cnt == 0) r = 0.f;
  qstar[(size_t)g * 512 + FF + tid] = r;
  q16out[(size_t)g * 512 + FF + tid] = (_Float16)r;
}

// ---------------- launcher ----------------
extern "C" void kernel_launch(void* const* d_in, const int* in_sizes, int n_in,
                              void* d_out, int out_size, void* d_ws, size_t ws_size,
                              hipStream_t stream) {
  const float* x   = (const float*)d_in[0];
  const int* batch = (const int*)d_in[1];
  // d_in[2] = size (4096), hard-coded
  const float* Wih = (const float*)d_in[3];
  const float* Whh = (const float*)d_in[4];
  const float* bih = (const float*)d_in[5];
  const float* bhh = (const float*)d_in[6];
  float* qstar = (float*)d_out;  // [GG, 512]; final value IS the output

  uint8_t* p = (uint8_t*)d_ws;
  auto alloc = [&](size_t bytes) {
    uint8_t* q = p;
    p += (bytes + 255) & ~(size_t)255;
    return q;
  };
  float* c_st    = (float*)alloc((size_t)GG * FF * 4);            // 4 MB
  _Float16* q16a = (_Float16*)alloc((size_t)GG * 2 * FF * 2);     // 4 MB
  _Float16* q16b = (_Float16*)alloc((size_t)GG * 2 * FF * 2);     // 4 MB
  _Float16* w16  = (_Float16*)alloc((size_t)4 * FF * 2 * FF * 2); // 1 MB
  float* bias    = (float*)alloc((size_t)4 * FF * 4);
  int* starts    = (int*)alloc((size_t)(GG + 1) * 4);
  _Float16* x16  = (_Float16*)alloc((size_t)NN * FF * 2);         // 128 MB
  bool use16 = ((size_t)(p - (uint8_t*)d_ws) <= ws_size);

  prep_w_kernel<<<(4 * FF * 2 * FF + 255) / 256, 256, 0, stream>>>(
      Wih, Whh, bih, bhh, w16, bias);
  find_starts_kernel<<<(GG + 1 + 255) / 256, 256, 0, stream>>>(batch, starts);

  if (use16) {
    // t = 0: bias-only LSTM, read x32 (non-temporal), write x16 mirror
    attn_kernel<true, 1><<<GG, 256, 0, stream>>>(
        x, nullptr, x16, starts, bias, c_st, qstar, q16a);
    for (int t = 1; t < TT; ++t) {
      _Float16* qin  = (t & 1) ? q16a : q16b;
      _Float16* qout = (t & 1) ? q16b : q16a;
      gemm_lstm_kernel<<<dim3(64, 8), 256, 0, stream>>>(
          qin, w16, bias, c_st, qstar, qout);
      attn_kernel<false, 2><<<GG, 256, 0, stream>>>(
          nullptr, x16, nullptr, starts, bias, c_st, qstar, qout);
    }
  } else {  // workspace too small for x16 mirror: f32 path
    attn_kernel<true, 0><<<GG, 256, 0, stream>>>(
        x, nullptr, nullptr, starts, bias, c_st, qstar, q16a);
    for (int t = 1; t < TT; ++t) {
      _Float16* qin  = (t & 1) ? q16a : q16b;
      _Float16* qout = (t & 1) ? q16b : q16a;
      gemm_lstm_kernel<<<dim3(64, 8), 256, 0, stream>>>(
          qin, w16, bias, c_st, qstar, qout);
      attn_kernel<false, 0><<<GG, 256, 0, stream>>>(
          x, nullptr, nullptr, starts, bias, c_st, qstar, qout);
    }
  }
}